// Round 2
// baseline (2286.078 us; speedup 1.0000x reference)
//
#include <hip/hip_runtime.h>
#include <hip/hip_bf16.h>

// Problem constants
#define B_   4
#define S_   2048
#define H_   16
#define HD_  64
#define D_   1024
#define M_   (B_ * S_)   // 8192 rows

typedef unsigned short u16;
typedef __bf16 bf16x8 __attribute__((ext_vector_type(8)));
typedef float  f32x4  __attribute__((ext_vector_type(4)));
typedef unsigned short ushort8 __attribute__((ext_vector_type(8)));

__device__ __forceinline__ float b2f(u16 u) {
    unsigned int x = ((unsigned int)u) << 16;
    return __builtin_bit_cast(float, x);
}
__device__ __forceinline__ u16 f2b(float f) {
    unsigned int x = __builtin_bit_cast(unsigned int, f);
    x += 0x7fffu + ((x >> 16) & 1u);   // RNE
    return (u16)(x >> 16);
}

// Load 8 elements of A starting at column offset, as bf16 u16x8.
__device__ __forceinline__ ushort8 loadA8(const float* p) {
    float4 a = *(const float4*)p;
    float4 b = *(const float4*)(p + 4);
    return ushort8{f2b(a.x), f2b(a.y), f2b(a.z), f2b(a.w),
                   f2b(b.x), f2b(b.y), f2b(b.z), f2b(b.w)};
}
__device__ __forceinline__ ushort8 loadA8(const u16* p) {
    return *(const ushort8*)p;
}

// ---------------------------------------------------------------------------
// Weight transpose + downcast: in fp32 [R][C] -> out bf16 [C][R]
// ---------------------------------------------------------------------------
__global__ __launch_bounds__(256) void transpose_k(const float* __restrict__ in,
                                                   u16* __restrict__ out,
                                                   int R, int C) {
    __shared__ u16 t[32][33];
    const int x0 = blockIdx.x * 32, y0 = blockIdx.y * 32;
    const int tx = threadIdx.x, ty = threadIdx.y;  // 32 x 8
#pragma unroll
    for (int i = 0; i < 32; i += 8)
        t[ty + i][tx] = f2b(in[(size_t)(y0 + ty + i) * C + x0 + tx]);
    __syncthreads();
#pragma unroll
    for (int i = 0; i < 32; i += 8)
        out[(size_t)(x0 + ty + i) * R + y0 + tx] = t[tx][ty + i];
}

// ---------------------------------------------------------------------------
// GEMM: C[M,N] = A[M,K] @ W[K,N] + bias, Bt = W^T as bf16 [N,K].
// A is fp32 or bf16 (converted during staging). fp32 MFMA accum.
// 128x128 tile, BK=32, 256 threads (2x2 waves of 64x64).
// ---------------------------------------------------------------------------
#define BM 128
#define BN 128
#define BK 32
#define LDST 56   // LDS row stride (elems); 112B rows -> 16B aligned

template <typename AT, typename OT>
__global__ __launch_bounds__(256) void gemm_bias_k(
    const AT* __restrict__ A, const u16* __restrict__ Bt,
    const float* __restrict__ bias, OT* __restrict__ C,
    int M, int N, int K)
{
    __shared__ u16 As[BM * LDST];
    __shared__ u16 Bs[BN * LDST];

    const int tid  = threadIdx.x;
    const int lane = tid & 63;
    const int wave = tid >> 6;
    const int wr = wave >> 1, wc = wave & 1;     // 2x2 wave grid, each 64x64
    const int l15 = lane & 15, quad = lane >> 4;
    const int m0 = blockIdx.y * BM, n0 = blockIdx.x * BN;

    const int srow = tid >> 2;          // 0..63
    const int skk  = (tid & 3) * 8;     // 0,8,16,24

    f32x4 acc[4][4] = {};

    for (int k0 = 0; k0 < K; k0 += BK) {
#pragma unroll
        for (int it = 0; it < 2; ++it) {
            int r = srow + it * 64;
            ushort8 av = loadA8(A + (size_t)(m0 + r) * K + k0 + skk);
            ushort8 bv = *(const ushort8*)(Bt + (size_t)(n0 + r) * K + k0 + skk);
            *(ushort8*)(As + r * LDST + skk) = av;
            *(ushort8*)(Bs + r * LDST + skk) = bv;
        }
        __syncthreads();
        bf16x8 af[4], bfr[4];
#pragma unroll
        for (int t = 0; t < 4; ++t) {
            af[t]  = *(const bf16x8*)(As + (wr * 64 + t * 16 + l15) * LDST + quad * 8);
            bfr[t] = *(const bf16x8*)(Bs + (wc * 64 + t * 16 + l15) * LDST + quad * 8);
        }
#pragma unroll
        for (int mt = 0; mt < 4; ++mt)
#pragma unroll
            for (int nt = 0; nt < 4; ++nt)
                acc[mt][nt] = __builtin_amdgcn_mfma_f32_16x16x32_bf16(
                    af[mt], bfr[nt], acc[mt][nt], 0, 0, 0);
        __syncthreads();
    }

#pragma unroll
    for (int nt = 0; nt < 4; ++nt) {
        int col = n0 + wc * 64 + nt * 16 + l15;
        float bv = bias[col];
#pragma unroll
        for (int mt = 0; mt < 4; ++mt) {
            int rbase = m0 + wr * 64 + mt * 16 + quad * 4;
#pragma unroll
            for (int r2 = 0; r2 < 4; ++r2) {
                float v = acc[mt][nt][r2] + bv;
                if constexpr (sizeof(OT) == 2)
                    C[(size_t)(rbase + r2) * N + col] = f2b(v);
                else
                    C[(size_t)(rbase + r2) * N + col] = v;
            }
        }
    }
}

// ---------------------------------------------------------------------------
// Causal flash attention, fp32 VALU. Q/K/V bf16 in ws, layout [B,S,H,HD].
// Grid (S/TQ, B*H), 256 threads. Each lane owns q-row q0+lane; the 4 waves
// process interleaved key tiles (TK=16), merge partials through LDS.
// ---------------------------------------------------------------------------
#define TQ 64
#define TK 16
#define KVSTR 68   // fp32 LDS row stride: 272B -> 16B aligned

__global__ __launch_bounds__(256) void attn_k(
    const u16* __restrict__ Qm, const u16* __restrict__ Km,
    const u16* __restrict__ Vm, u16* __restrict__ Om)
{
    __shared__ float smem[2 * 4 * TK * KVSTR];  // K tiles (64 rows) + V tiles
    float* Ks = smem;
    float* Vs = smem + 4 * TK * KVSTR;

    const int tid  = threadIdx.x;
    const int lane = tid & 63;
    const int wave = tid >> 6;
    const int bh = blockIdx.y;
    const int b = bh >> 4, h = bh & (H_ - 1);
    const int q0 = blockIdx.x * TQ;
    const int qi = q0 + lane;

    // q row -> registers, pre-scaled by 1/sqrt(HD)
    float qreg[HD_];
    {
        const u16* qp = Qm + (((size_t)(b * S_ + qi)) * H_ + h) * HD_;
#pragma unroll
        for (int i = 0; i < 8; ++i) {
            ushort8 u = *(const ushort8*)(qp + i * 8);
#pragma unroll
            for (int j2 = 0; j2 < 8; ++j2) qreg[i * 8 + j2] = b2f(u[j2]) * 0.125f;
        }
    }
    float oreg[HD_];
#pragma unroll
    for (int d = 0; d < HD_; ++d) oreg[d] = 0.f;
    float mrun = -INFINITY, lrun = 0.f;

    const int ntiles = (q0 + TQ) / TK;  // multiple of 4
    const int srow  = tid >> 2;         // 0..63: staged key row
    const int squar = (tid & 3) * 16;   // quarter of head dim

    for (int t0 = 0; t0 < ntiles; t0 += 4) {
        __syncthreads();
        {   // stage 64 keys (4 tiles) of K and V as fp32
            int kidx = t0 * TK + srow;
            const u16* kp = Km + (((size_t)(b * S_ + kidx)) * H_ + h) * HD_ + squar;
            const u16* vp = Vm + (((size_t)(b * S_ + kidx)) * H_ + h) * HD_ + squar;
#pragma unroll
            for (int i = 0; i < 2; ++i) {
                ushort8 ku = *(const ushort8*)(kp + i * 8);
                ushort8 vu = *(const ushort8*)(vp + i * 8);
                float4 ka{b2f(ku[0]), b2f(ku[1]), b2f(ku[2]), b2f(ku[3])};
                float4 kb{b2f(ku[4]), b2f(ku[5]), b2f(ku[6]), b2f(ku[7])};
                float4 va{b2f(vu[0]), b2f(vu[1]), b2f(vu[2]), b2f(vu[3])};
                float4 vb{b2f(vu[4]), b2f(vu[5]), b2f(vu[6]), b2f(vu[7])};
                int base = srow * KVSTR + squar + i * 8;
                *(float4*)&Ks[base]     = ka;
                *(float4*)&Ks[base + 4] = kb;
                *(float4*)&Vs[base]     = va;
                *(float4*)&Vs[base + 4] = vb;
            }
        }
        __syncthreads();

        const int tile = t0 + wave;
        const int k0 = tile * TK;
        const float* KsW = Ks + (size_t)wave * TK * KVSTR;
        const float* VsW = Vs + (size_t)wave * TK * KVSTR;

        float s[TK];
        float tmax = -INFINITY;
#pragma unroll
        for (int j = 0; j < TK; ++j) {
            const float* kr = KsW + j * KVSTR;
            float a0 = 0.f, a1 = 0.f, a2 = 0.f, a3 = 0.f;
#pragma unroll
            for (int d4 = 0; d4 < 16; ++d4) {
                float4 kv = *(const float4*)(kr + d4 * 4);
                a0 = fmaf(qreg[d4 * 4 + 0], kv.x, a0);
                a1 = fmaf(qreg[d4 * 4 + 1], kv.y, a1);
                a2 = fmaf(qreg[d4 * 4 + 2], kv.z, a2);
                a3 = fmaf(qreg[d4 * 4 + 3], kv.w, a3);
            }
            float sc = (a0 + a1) + (a2 + a3);
            s[j] = (k0 + j <= qi) ? sc : -INFINITY;
            tmax = fmaxf(tmax, s[j]);
        }
        float mn = fmaxf(mrun, tmax);
        float msafe = (mn == -INFINITY) ? 0.f : mn;  // all-masked tile -> no-op
        float alpha = __expf(mrun - msafe);          // mrun=-inf -> 0
        lrun *= alpha;
#pragma unroll
        for (int d = 0; d < HD_; ++d) oreg[d] *= alpha;
#pragma unroll
        for (int j = 0; j < TK; ++j) {
            float p = __expf(s[j] - msafe);          // masked -> 0
            lrun += p;
            const float* vr = VsW + j * KVSTR;
#pragma unroll
            for (int d4 = 0; d4 < 16; ++d4) {
                float4 vv = *(const float4*)(vr + d4 * 4);
                oreg[d4 * 4 + 0] = fmaf(p, vv.x, oreg[d4 * 4 + 0]);
                oreg[d4 * 4 + 1] = fmaf(p, vv.y, oreg[d4 * 4 + 1]);
                oreg[d4 * 4 + 2] = fmaf(p, vv.z, oreg[d4 * 4 + 2]);
                oreg[d4 * 4 + 3] = fmaf(p, vv.w, oreg[d4 * 4 + 3]);
            }
        }
        mrun = mn;
    }

    // Merge the 4 waves' partials (wave0 accumulates), via LDS.
    float* mb = smem;
#pragma unroll 1
    for (int w = 1; w < 4; ++w) {
        __syncthreads();
        if (wave == w) {
            float* dst = mb + lane * KVSTR;
#pragma unroll
            for (int d = 0; d < HD_; ++d) dst[d] = oreg[d];
            dst[64] = mrun; dst[65] = lrun;
        }
        __syncthreads();
        if (wave == 0) {
            const float* src = mb + lane * KVSTR;
            float mw = src[64], lw = src[65];
            float mn = fmaxf(mrun, mw);              // mrun finite for wave0
            float sc0 = __expf(mrun - mn);
            float scw = __expf(mw - mn);             // mw=-inf -> 0
            lrun = lrun * sc0 + lw * scw;
#pragma unroll
            for (int d = 0; d < HD_; ++d)
                oreg[d] = oreg[d] * sc0 + src[d] * scw;
            mrun = mn;
        }
    }
    if (wave == 0) {
        float inv = 1.f / lrun;
        u16* op = Om + (((size_t)(b * S_ + qi)) * H_ + h) * HD_;
#pragma unroll
        for (int d = 0; d < HD_; ++d) op[d] = f2b(oreg[d] * inv);
    }
}

// ---------------------------------------------------------------------------
extern "C" void kernel_launch(void* const* d_in, const int* in_sizes, int n_in,
                              void* d_out, int out_size, void* d_ws, size_t ws_size,
                              hipStream_t stream)
{
    (void)in_sizes; (void)n_in; (void)out_size; (void)ws_size;
    const float* x  = (const float*)d_in[0];
    const float* Wq = (const float*)d_in[1];
    const float* bq = (const float*)d_in[2];
    const float* Wk = (const float*)d_in[3];
    const float* bk = (const float*)d_in[4];
    const float* Wv = (const float*)d_in[5];
    const float* bv = (const float*)d_in[6];
    const float* Wo = (const float*)d_in[7];
    const float* bo = (const float*)d_in[8];

    u16* ws = (u16*)d_ws;
    const size_t MD = (size_t)M_ * D_;
    const size_t DD = (size_t)D_ * D_;
    u16* Qb  = ws;            // bf16 [B,S,H,HD]
    u16* Kb  = Qb + MD;
    u16* Vb  = Kb + MD;
    u16* Cb  = Vb + MD;       // attention context, bf16 [M, D]
    u16* WqT = Cb + MD;       // bf16 [N,K] transposed weights
    u16* WkT = WqT + DD;
    u16* WvT = WkT + DD;
    u16* WoT = WvT + DD;

    dim3 tg(D_ / 32, D_ / 32), tb(32, 8);
    transpose_k<<<tg, tb, 0, stream>>>(Wq, WqT, D_, D_);
    transpose_k<<<tg, tb, 0, stream>>>(Wk, WkT, D_, D_);
    transpose_k<<<tg, tb, 0, stream>>>(Wv, WvT, D_, D_);
    transpose_k<<<tg, tb, 0, stream>>>(Wo, WoT, D_, D_);

    dim3 gg(D_ / BN, M_ / BM);  // (8, 64)
    gemm_bias_k<float, u16><<<gg, 256, 0, stream>>>(x, WqT, bq, Qb, M_, D_, D_);
    gemm_bias_k<float, u16><<<gg, 256, 0, stream>>>(x, WkT, bk, Kb, M_, D_, D_);
    gemm_bias_k<float, u16><<<gg, 256, 0, stream>>>(x, WvT, bv, Vb, M_, D_, D_);

    attn_k<<<dim3(S_ / TQ, B_ * H_), 256, 0, stream>>>(Qb, Kb, Vb, Cb);

    gemm_bias_k<u16, float><<<gg, 256, 0, stream>>>(Cb, WoT, bo, (float*)d_out, M_, D_, D_);
}

// Round 4
// 407.563 us; speedup vs baseline: 5.6091x; 5.6091x over previous
//
#include <hip/hip_runtime.h>
#include <hip/hip_bf16.h>

// Problem constants
#define B_   4
#define S_   2048
#define H_   16
#define HD_  64
#define D_   1024
#define M_   (B_ * S_)   // 8192 rows

typedef unsigned short u16;
typedef __bf16 bf16x8 __attribute__((ext_vector_type(8)));
typedef float  f32x4  __attribute__((ext_vector_type(4)));
typedef unsigned short u16x8 __attribute__((ext_vector_type(8)));
typedef unsigned short u16x4 __attribute__((ext_vector_type(4)));

__device__ __forceinline__ float b2f(u16 u) {
    unsigned int x = ((unsigned int)u) << 16;
    return __builtin_bit_cast(float, x);
}
__device__ __forceinline__ u16 f2b(float f) {
    unsigned int x = __builtin_bit_cast(unsigned int, f);
    x += 0x7fffu + ((x >> 16) & 1u);   // RNE
    return (u16)(x >> 16);
}

// Load 8 elements of A starting at column offset, as bf16 u16x8.
__device__ __forceinline__ u16x8 loadA8(const float* p) {
    float4 a = *(const float4*)p;
    float4 b = *(const float4*)(p + 4);
    return u16x8{f2b(a.x), f2b(a.y), f2b(a.z), f2b(a.w),
                 f2b(b.x), f2b(b.y), f2b(b.z), f2b(b.w)};
}
__device__ __forceinline__ u16x8 loadA8(const u16* p) {
    return *(const u16x8*)p;
}

// ---------------------------------------------------------------------------
// Weight transpose + downcast: in fp32 [R][C] -> out bf16 [C][R]
// ---------------------------------------------------------------------------
__global__ __launch_bounds__(256) void transpose_k(const float* __restrict__ in,
                                                   u16* __restrict__ out,
                                                   int R, int C) {
    __shared__ u16 t[32][33];
    const int x0 = blockIdx.x * 32, y0 = blockIdx.y * 32;
    const int tx = threadIdx.x, ty = threadIdx.y;  // 32 x 8
#pragma unroll
    for (int i = 0; i < 32; i += 8)
        t[ty + i][tx] = f2b(in[(size_t)(y0 + ty + i) * C + x0 + tx]);
    __syncthreads();
#pragma unroll
    for (int i = 0; i < 32; i += 8)
        out[(size_t)(x0 + ty + i) * R + y0 + tx] = t[tx][ty + i];
}

// ---------------------------------------------------------------------------
// GEMM: C[M,N] = A[M,K] @ W[K,N] + bias, Bt = W^T as bf16 [N,K].
// OUT_MODE: 0 = bf16 [M,N], 1 = fp32 [M,N], 2 = bf16 transposed-per-head
// [B,H,HD,S] (for V so attention can read V^T rows directly).
// ---------------------------------------------------------------------------
#define BM 128
#define BN 128
#define BK 32
#define LDST 56   // LDS row stride (elems); 112B rows -> 16B aligned

template <typename AT, int OUT_MODE>
__global__ __launch_bounds__(256) void gemm_bias_k(
    const AT* __restrict__ A, const u16* __restrict__ Bt,
    const float* __restrict__ bias, void* __restrict__ Cv,
    int M, int N, int K)
{
    __shared__ u16 As[BM * LDST];
    __shared__ u16 Bs[BN * LDST];

    const int tid  = threadIdx.x;
    const int lane = tid & 63;
    const int wave = tid >> 6;
    const int wr = wave >> 1, wc = wave & 1;     // 2x2 wave grid, each 64x64
    const int l15 = lane & 15, quad = lane >> 4;
    const int m0 = blockIdx.y * BM, n0 = blockIdx.x * BN;

    const int srow = tid >> 2;          // 0..63
    const int skk  = (tid & 3) * 8;     // 0,8,16,24

    f32x4 acc[4][4] = {};

    for (int k0 = 0; k0 < K; k0 += BK) {
#pragma unroll
        for (int it = 0; it < 2; ++it) {
            int r = srow + it * 64;
            u16x8 av = loadA8(A + (size_t)(m0 + r) * K + k0 + skk);
            u16x8 bv = *(const u16x8*)(Bt + (size_t)(n0 + r) * K + k0 + skk);
            *(u16x8*)(As + r * LDST + skk) = av;
            *(u16x8*)(Bs + r * LDST + skk) = bv;
        }
        __syncthreads();
        bf16x8 af[4], bfr[4];
#pragma unroll
        for (int t = 0; t < 4; ++t) {
            af[t]  = *(const bf16x8*)(As + (wr * 64 + t * 16 + l15) * LDST + quad * 8);
            bfr[t] = *(const bf16x8*)(Bs + (wc * 64 + t * 16 + l15) * LDST + quad * 8);
        }
#pragma unroll
        for (int mt = 0; mt < 4; ++mt)
#pragma unroll
            for (int nt = 0; nt < 4; ++nt)
                acc[mt][nt] = __builtin_amdgcn_mfma_f32_16x16x32_bf16(
                    af[mt], bfr[nt], acc[mt][nt], 0, 0, 0);
        __syncthreads();
    }

#pragma unroll
    for (int nt = 0; nt < 4; ++nt) {
        int col = n0 + wc * 64 + nt * 16 + l15;
        float bv = bias[col];
#pragma unroll
        for (int mt = 0; mt < 4; ++mt) {
            int rbase = m0 + wr * 64 + mt * 16 + quad * 4;
            if constexpr (OUT_MODE == 2) {
                // Vt layout [B][H][HD][S]; rows rbase..rbase+3 are consecutive s
                int bidx = rbase >> 11, s = rbase & (S_ - 1);
                int hh = col >> 6, hd = col & 63;
                u16* C = (u16*)Cv;
                u16x4 pk{f2b(acc[mt][nt][0] + bv), f2b(acc[mt][nt][1] + bv),
                         f2b(acc[mt][nt][2] + bv), f2b(acc[mt][nt][3] + bv)};
                *(u16x4*)(C + (((size_t)(bidx * H_ + hh)) * HD_ + hd) * S_ + s) = pk;
            } else {
#pragma unroll
                for (int r2 = 0; r2 < 4; ++r2) {
                    float v = acc[mt][nt][r2] + bv;
                    if constexpr (OUT_MODE == 0)
                        ((u16*)Cv)[(size_t)(rbase + r2) * N + col] = f2b(v);
                    else
                        ((float*)Cv)[(size_t)(rbase + r2) * N + col] = v;
                }
            }
        }
    }
}

// ---------------------------------------------------------------------------
// Causal flash attention with MFMA (bf16 in, fp32 softmax state).
// Q,K in [B,S,H,HD]; V pre-transposed as Vt [B,H,HD,S]. Out ctx [M, D] bf16.
//
// Block: 64 q-rows of one (b,h); 4 waves each own 16 q rows (no cross-wave
// merge). K-tiles of 64 keys staged in LDS (XOR-swizzled 16B chunks ->
// conflict-free b128 access). Per tile:
//   S^T = K.Q^T  (mfma, A=K rows m=key, B=Q rows n=q)
//   softmax on S^T frags: q = lane&15, keys = quad*4+reg -> 2 shfl_xor reduce
//   P^T -> per-wave LDS scratch (C-layout writes, B-layout reads, swizzled)
//   ctx^T += Vt.P^T (mfma, A=Vt rows m=d)
// Epilogue: normalize, transpose 16x64 tile through the same scratch, store.
// ---------------------------------------------------------------------------
__global__ __launch_bounds__(256) void attn_mfma_k(
    const u16* __restrict__ Qm, const u16* __restrict__ Km,
    const u16* __restrict__ Vtg, u16* __restrict__ Om)
{
    __shared__ u16 Ks[64 * 64];
    __shared__ u16 Vs[64 * 64];
    __shared__ u16 Ps[4][16 * 64];

    const int tid  = threadIdx.x;
    const int lane = tid & 63;
    const int wave = tid >> 6;
    const int l15  = lane & 15;
    const int quad = lane >> 4;
    const int bh = blockIdx.y, b = bh >> 4, h = bh & (H_ - 1);
    const int q0 = blockIdx.x * 64;
    const int qg = q0 + wave * 16 + l15;   // this lane's q column (B-frag n)

    // Q B-frags: n = l15 (q row qg), k = quad*8 + j (+32)
    bf16x8 qf[2];
    {
        const u16* qp = Qm + (((size_t)(b * S_ + qg)) * H_ + h) * HD_ + quad * 8;
        qf[0] = *(const bf16x8*)qp;
        qf[1] = *(const bf16x8*)(qp + 32);
    }

    f32x4 of[4] = {};                   // ctx^T frags: d = 16dt+4quad+reg, q=l15
    float mrun = -INFINITY, lrun = 0.f;

    const int ntiles = blockIdx.x + 1;
    const int srow = tid >> 2;          // staging row 0..63
    const int sch  = (tid & 3) * 2;     // staging chunk pair
    const u16* Kg = Km  + (((size_t)(b * S_)) * H_ + h) * HD_;
    const u16* Vg = Vtg + (((size_t)(b * H_ + h)) * HD_) * S_;
    const float cscale = 0.18033688011112042f;  // log2(e)/sqrt(64)

    for (int t = 0; t < ntiles; ++t) {
        const int k0 = t * 64;
        __syncthreads();
        {   // stage K tile [key][d] and Vt tile [d][key], swizzled chunks
            const int sw = srow & 7;
            const u16* gk = Kg + (size_t)(k0 + srow) * (H_ * HD_) + sch * 8;
            u16x8 ka = *(const u16x8*)gk;
            u16x8 kb = *(const u16x8*)(gk + 8);
            *(u16x8*)(Ks + srow * 64 + ((sch    ) ^ sw) * 8) = ka;
            *(u16x8*)(Ks + srow * 64 + ((sch + 1) ^ sw) * 8) = kb;
            const u16* gv = Vg + (size_t)srow * S_ + k0 + sch * 8;
            u16x8 va = *(const u16x8*)gv;
            u16x8 vb = *(const u16x8*)(gv + 8);
            *(u16x8*)(Vs + srow * 64 + ((sch    ) ^ sw) * 8) = va;
            *(u16x8*)(Vs + srow * 64 + ((sch + 1) ^ sw) * 8) = vb;
        }
        __syncthreads();

        // S^T = K.Q^T : 4 key sub-tiles of 16
        f32x4 sf[4];
#pragma unroll
        for (int kt = 0; kt < 4; ++kt) {
            const int krow = kt * 16 + l15;
            const int sw = krow & 7;
            bf16x8 a0 = *(const bf16x8*)(Ks + krow * 64 + ((quad    ) ^ sw) * 8);
            bf16x8 a1 = *(const bf16x8*)(Ks + krow * 64 + ((quad + 4) ^ sw) * 8);
            f32x4 acc = {};
            acc = __builtin_amdgcn_mfma_f32_16x16x32_bf16(a0, qf[0], acc, 0, 0, 0);
            acc = __builtin_amdgcn_mfma_f32_16x16x32_bf16(a1, qf[1], acc, 0, 0, 0);
            sf[kt] = acc;
        }

        // scale (exp2 domain) + causal mask (only last tile can be diagonal)
        const bool diag = (t == ntiles - 1);
        float s[16];
        float tmax = -INFINITY;
#pragma unroll
        for (int kt = 0; kt < 4; ++kt)
#pragma unroll
            for (int r = 0; r < 4; ++r) {
                float v = sf[kt][r] * cscale;
                if (diag && (k0 + kt * 16 + quad * 4 + r > qg)) v = -INFINITY;
                s[kt * 4 + r] = v;
                tmax = fmaxf(tmax, v);
            }
        tmax = fmaxf(tmax, __shfl_xor(tmax, 16));
        tmax = fmaxf(tmax, __shfl_xor(tmax, 32));
        const float mnew = fmaxf(mrun, tmax);
        const float alpha = __builtin_amdgcn_exp2f(mrun - mnew);  // first tile: 0
        mrun = mnew;
        float ls = 0.f;
        u16 pb[16];
#pragma unroll
        for (int i = 0; i < 16; ++i) {
            float p = __builtin_amdgcn_exp2f(s[i] - mnew);
            ls += p;
            pb[i] = f2b(p);
        }
        ls += __shfl_xor(ls, 16);
        ls += __shfl_xor(ls, 32);
        lrun = lrun * alpha + ls;
#pragma unroll
        for (int dt = 0; dt < 4; ++dt)
#pragma unroll
            for (int r = 0; r < 4; ++r) of[dt][r] *= alpha;

        // P^T -> per-wave scratch: row q=l15, keys packed, swizzled chunks
        u16* pw = Ps[wave];
#pragma unroll
        for (int kt = 0; kt < 4; ++kt) {
            const int g = kt * 16 + quad * 4;
            const int pos = ((g >> 3) ^ (l15 & 7)) * 8 + (g & 7);
            *(u16x4*)(pw + l15 * 64 + pos) =
                u16x4{pb[kt * 4], pb[kt * 4 + 1], pb[kt * 4 + 2], pb[kt * 4 + 3]};
        }
        // B-frags of P^T: n=q=l15, k = quad*8+j (+32)
        bf16x8 pf[2];
#pragma unroll
        for (int hf = 0; hf < 2; ++hf) {
            const int ch = (quad + 4 * hf) ^ (l15 & 7);
            pf[hf] = *(const bf16x8*)(pw + l15 * 64 + ch * 8);
        }
        // ctx^T += Vt.P^T
#pragma unroll
        for (int dt = 0; dt < 4; ++dt) {
            const int drow = dt * 16 + l15;
            const int sw = drow & 7;
            bf16x8 v0 = *(const bf16x8*)(Vs + drow * 64 + ((quad    ) ^ sw) * 8);
            bf16x8 v1 = *(const bf16x8*)(Vs + drow * 64 + ((quad + 4) ^ sw) * 8);
            of[dt] = __builtin_amdgcn_mfma_f32_16x16x32_bf16(v0, pf[0], of[dt], 0, 0, 0);
            of[dt] = __builtin_amdgcn_mfma_f32_16x16x32_bf16(v1, pf[1], of[dt], 0, 0, 0);
        }
    }

    // Epilogue: normalize, transpose 16q x 64d through per-wave scratch, store.
    const float inv = 1.f / lrun;
    u16* pw = Ps[wave];
#pragma unroll
    for (int dt = 0; dt < 4; ++dt) {
        const int g = dt * 16 + quad * 4;
        const int pos = ((g >> 3) ^ (l15 & 7)) * 8 + (g & 7);
        *(u16x4*)(pw + l15 * 64 + pos) =
            u16x4{f2b(of[dt][0] * inv), f2b(of[dt][1] * inv),
                  f2b(of[dt][2] * inv), f2b(of[dt][3] * inv)};
    }
    {
        const int r = lane >> 2;          // local q row 0..15
        const int cp = lane & 3;          // 16-d column group
        u16x8 o0 = *(const u16x8*)(pw + r * 64 + ((2 * cp    ) ^ (r & 7)) * 8);
        u16x8 o1 = *(const u16x8*)(pw + r * 64 + ((2 * cp + 1) ^ (r & 7)) * 8);
        u16* op = Om + ((size_t)(b * S_ + q0 + wave * 16 + r)) * D_ + h * 64 + cp * 16;
        *(u16x8*)op = o0;
        *(u16x8*)(op + 8) = o1;
    }
}

// ---------------------------------------------------------------------------
extern "C" void kernel_launch(void* const* d_in, const int* in_sizes, int n_in,
                              void* d_out, int out_size, void* d_ws, size_t ws_size,
                              hipStream_t stream)
{
    (void)in_sizes; (void)n_in; (void)out_size; (void)ws_size;
    const float* x  = (const float*)d_in[0];
    const float* Wq = (const float*)d_in[1];
    const float* bq = (const float*)d_in[2];
    const float* Wk = (const float*)d_in[3];
    const float* bk = (const float*)d_in[4];
    const float* Wv = (const float*)d_in[5];
    const float* bv = (const float*)d_in[6];
    const float* Wo = (const float*)d_in[7];
    const float* bo = (const float*)d_in[8];

    u16* ws = (u16*)d_ws;
    const size_t MD = (size_t)M_ * D_;
    const size_t DD = (size_t)D_ * D_;
    u16* Qb  = ws;            // bf16 [B,S,H,HD]
    u16* Kb  = Qb + MD;       // bf16 [B,S,H,HD]
    u16* Vtb = Kb + MD;       // bf16 [B,H,HD,S]  (transposed V)
    u16* Cb  = Vtb + MD;      // attention context, bf16 [M, D]
    u16* WqT = Cb + MD;       // bf16 [N,K] transposed weights
    u16* WkT = WqT + DD;
    u16* WvT = WkT + DD;
    u16* WoT = WvT + DD;

    dim3 tg(D_ / 32, D_ / 32), tb(32, 8);
    transpose_k<<<tg, tb, 0, stream>>>(Wq, WqT, D_, D_);
    transpose_k<<<tg, tb, 0, stream>>>(Wk, WkT, D_, D_);
    transpose_k<<<tg, tb, 0, stream>>>(Wv, WvT, D_, D_);
    transpose_k<<<tg, tb, 0, stream>>>(Wo, WoT, D_, D_);

    dim3 gg(D_ / BN, M_ / BM);  // (8, 64)
    gemm_bias_k<float, 0><<<gg, 256, 0, stream>>>(x, WqT, bq, Qb,  M_, D_, D_);
    gemm_bias_k<float, 0><<<gg, 256, 0, stream>>>(x, WkT, bk, Kb,  M_, D_, D_);
    gemm_bias_k<float, 2><<<gg, 256, 0, stream>>>(x, WvT, bv, Vtb, M_, D_, D_);

    attn_mfma_k<<<dim3(S_ / 64, B_ * H_), 256, 0, stream>>>(Qb, Kb, Vtb, Cb);

    gemm_bias_k<u16, 1><<<gg, 256, 0, stream>>>(Cb, WoT, bo, d_out, M_, D_, D_);
}

// Round 5
// 367.800 us; speedup vs baseline: 6.2155x; 1.1081x over previous
//
#include <hip/hip_runtime.h>
#include <hip/hip_bf16.h>

// Problem constants
#define B_   4
#define S_   2048
#define H_   16
#define HD_  64
#define D_   1024
#define M_   (B_ * S_)   // 8192 rows

typedef unsigned short u16;
typedef __bf16 bf16x8 __attribute__((ext_vector_type(8)));
typedef float  f32x4  __attribute__((ext_vector_type(4)));
typedef unsigned short u16x8 __attribute__((ext_vector_type(8)));
typedef unsigned short u16x4 __attribute__((ext_vector_type(4)));

__device__ __forceinline__ float b2f(u16 u) {
    unsigned int x = ((unsigned int)u) << 16;
    return __builtin_bit_cast(float, x);
}
__device__ __forceinline__ u16 f2b(float f) {          // RNE
    unsigned int x = __builtin_bit_cast(unsigned int, f);
    x += 0x7fffu + ((x >> 16) & 1u);
    return (u16)(x >> 16);
}
__device__ __forceinline__ u16 f2bt(float f) {         // truncate (for P>=0)
    return (u16)(__builtin_bit_cast(unsigned int, f) >> 16);
}

// ---------------------------------------------------------------------------
// x fp32 -> bf16, flat
// ---------------------------------------------------------------------------
__global__ __launch_bounds__(256) void cvt_k(const float* __restrict__ in,
                                             u16* __restrict__ out) {
    size_t i = ((size_t)blockIdx.x * 256 + threadIdx.x) * 8;
    float4 a = *(const float4*)(in + i);
    float4 b = *(const float4*)(in + i + 4);
    *(u16x8*)(out + i) = u16x8{f2b(a.x), f2b(a.y), f2b(a.z), f2b(a.w),
                               f2b(b.x), f2b(b.y), f2b(b.z), f2b(b.w)};
}

// ---------------------------------------------------------------------------
// Weight transpose + downcast + scale: fp32 [R][C] -> bf16 [C][R] * scale
// ---------------------------------------------------------------------------
__global__ __launch_bounds__(256) void transpose_k(const float* __restrict__ in,
                                                   u16* __restrict__ out,
                                                   int R, int C, float scale) {
    __shared__ u16 t[32][33];
    const int x0 = blockIdx.x * 32, y0 = blockIdx.y * 32;
    const int tx = threadIdx.x, ty = threadIdx.y;  // 32 x 8
#pragma unroll
    for (int i = 0; i < 32; i += 8)
        t[ty + i][tx] = f2b(in[(size_t)(y0 + ty + i) * C + x0 + tx] * scale);
    __syncthreads();
#pragma unroll
    for (int i = 0; i < 32; i += 8)
        out[(size_t)(x0 + ty + i) * R + y0 + tx] = t[tx][ty + i];
}

// ---------------------------------------------------------------------------
// GEMM: C[M,N] = A[M,K] @ W[K,N] + bias*bscale. A bf16, Bt = W^T bf16 [N,K].
// OUT_MODE: 0 = bf16 [M,N], 1 = fp32 [M,N], 2 = bf16 Vt layout [B,H,HD,S].
// ---------------------------------------------------------------------------
#define BM 128
#define BN 128
#define BK 32
#define LDST 56   // LDS row stride (elems); 112B rows -> 16B aligned

template <int OUT_MODE>
__global__ __launch_bounds__(256) void gemm_bias_k(
    const u16* __restrict__ A, const u16* __restrict__ Bt,
    const float* __restrict__ bias, float bscale, void* __restrict__ Cv,
    int M, int N, int K)
{
    __shared__ u16 As[BM * LDST];
    __shared__ u16 Bs[BN * LDST];

    const int tid  = threadIdx.x;
    const int lane = tid & 63;
    const int wave = tid >> 6;
    const int wr = wave >> 1, wc = wave & 1;
    const int l15 = lane & 15, quad = lane >> 4;
    const int m0 = blockIdx.y * BM, n0 = blockIdx.x * BN;

    const int srow = tid >> 2;
    const int skk  = (tid & 3) * 8;

    f32x4 acc[4][4] = {};

    for (int k0 = 0; k0 < K; k0 += BK) {
#pragma unroll
        for (int it = 0; it < 2; ++it) {
            int r = srow + it * 64;
            u16x8 av = *(const u16x8*)(A  + (size_t)(m0 + r) * K + k0 + skk);
            u16x8 bv = *(const u16x8*)(Bt + (size_t)(n0 + r) * K + k0 + skk);
            *(u16x8*)(As + r * LDST + skk) = av;
            *(u16x8*)(Bs + r * LDST + skk) = bv;
        }
        __syncthreads();
        bf16x8 af[4], bfr[4];
#pragma unroll
        for (int t = 0; t < 4; ++t) {
            af[t]  = *(const bf16x8*)(As + (wr * 64 + t * 16 + l15) * LDST + quad * 8);
            bfr[t] = *(const bf16x8*)(Bs + (wc * 64 + t * 16 + l15) * LDST + quad * 8);
        }
#pragma unroll
        for (int mt = 0; mt < 4; ++mt)
#pragma unroll
            for (int nt = 0; nt < 4; ++nt)
                acc[mt][nt] = __builtin_amdgcn_mfma_f32_16x16x32_bf16(
                    af[mt], bfr[nt], acc[mt][nt], 0, 0, 0);
        __syncthreads();
    }

#pragma unroll
    for (int nt = 0; nt < 4; ++nt) {
        int col = n0 + wc * 64 + nt * 16 + l15;
        float bv = bias[col] * bscale;
#pragma unroll
        for (int mt = 0; mt < 4; ++mt) {
            int rbase = m0 + wr * 64 + mt * 16 + quad * 4;
            if constexpr (OUT_MODE == 2) {
                int bidx = rbase >> 11, s = rbase & (S_ - 1);
                int hh = col >> 6, hd = col & 63;
                u16* C = (u16*)Cv;
                u16x4 pk{f2b(acc[mt][nt][0] + bv), f2b(acc[mt][nt][1] + bv),
                         f2b(acc[mt][nt][2] + bv), f2b(acc[mt][nt][3] + bv)};
                *(u16x4*)(C + (((size_t)(bidx * H_ + hh)) * HD_ + hd) * S_ + s) = pk;
            } else {
#pragma unroll
                for (int r2 = 0; r2 < 4; ++r2) {
                    float v = acc[mt][nt][r2] + bv;
                    if constexpr (OUT_MODE == 0)
                        ((u16*)Cv)[(size_t)(rbase + r2) * N + col] = f2b(v);
                    else
                        ((float*)Cv)[(size_t)(rbase + r2) * N + col] = v;
                }
            }
        }
    }
}

// ---------------------------------------------------------------------------
// Causal flash attention, MFMA, no LDS staging, no barriers.
// Q pre-scaled by log2(e)/8 (folded into Wq/bq). K [B,S,H,HD], Vt [B,H,HD,S].
// Block = 4 q-tiles {j, 15-j, 16+j, 31-j} of one (b,h): 66 compute-passes per
// block (perfectly balanced). 4 waves split each q-tile (16 rows each).
// K/V fragments are 16B-contiguous global reads (L2-served), held in regs,
// amortized over up to 4 active q-subtiles. Softmax: p = exp2(s) directly
// (scores |s|<~9, safe in fp32), l reduced once at the end.
// P C-layout -> B-layout through per-wave swizzled LDS scratch (8 KB total).
// ---------------------------------------------------------------------------
__global__ __launch_bounds__(256) void attn_mfma_k(
    const u16* __restrict__ Qm, const u16* __restrict__ Km,
    const u16* __restrict__ Vtg, u16* __restrict__ Om)
{
    __shared__ u16 Ps[4][16 * 64];

    const int tid  = threadIdx.x;
    const int lane = tid & 63;
    const int wave = tid >> 6;
    const int l15  = lane & 15;
    const int quad = lane >> 4;
    const int bh = blockIdx.y, b = bh >> 4, h = bh & (H_ - 1);
    const int j  = blockIdx.x;                 // 0..7
    const int dg[4] = { j, 15 - j, 16 + j, 31 - j };

    const u16* Qg = Qm + (size_t)b * S_ * (H_ * HD_) + h * HD_;
    const u16* Kg = Km + (size_t)b * S_ * (H_ * HD_) + h * HD_;
    const u16* Vg = Vtg + ((size_t)(b * H_ + h)) * HD_ * S_;

    // Q B-frags (already in exp2 score domain via folded scale)
    bf16x8 qf[4][2];
#pragma unroll
    for (int qs = 0; qs < 4; ++qs) {
        const u16* qp = Qg + (size_t)(dg[qs] * 64 + wave * 16 + l15) * (H_ * HD_) + quad * 8;
        qf[qs][0] = *(const bf16x8*)qp;
        qf[qs][1] = *(const bf16x8*)(qp + 32);
    }

    f32x4 of[4][4] = {};     // ctx^T frags per qs: d=16dt+4quad+r, q=l15
    float lacc[4] = {0.f, 0.f, 0.f, 0.f};
    u16* pw = Ps[wave];

    const int T = 32 - j;
    for (int t = 0; t < T; ++t) {
        // K frags: A[m=key][k=d], 16B contiguous rows
        bf16x8 kf[4][2];
#pragma unroll
        for (int kt = 0; kt < 4; ++kt) {
            const u16* kp = Kg + (size_t)(t * 64 + kt * 16 + l15) * (H_ * HD_) + quad * 8;
            kf[kt][0] = *(const bf16x8*)kp;
            kf[kt][1] = *(const bf16x8*)(kp + 32);
        }
        // Vt frags: A[m=d][k=key], 16B contiguous rows
        bf16x8 vf[4][2];
#pragma unroll
        for (int dt = 0; dt < 4; ++dt) {
            const u16* vp = Vg + (size_t)(dt * 16 + l15) * S_ + t * 64 + quad * 8;
            vf[dt][0] = *(const bf16x8*)vp;
            vf[dt][1] = *(const bf16x8*)(vp + 32);
        }

#pragma unroll
        for (int qs = 0; qs < 4; ++qs) {
            if (t > dg[qs]) continue;          // wave-uniform
            // S^T = K.Q^T
            f32x4 sf[4];
#pragma unroll
            for (int kt = 0; kt < 4; ++kt) {
                f32x4 acc = {};
                acc = __builtin_amdgcn_mfma_f32_16x16x32_bf16(kf[kt][0], qf[qs][0], acc, 0, 0, 0);
                acc = __builtin_amdgcn_mfma_f32_16x16x32_bf16(kf[kt][1], qf[qs][1], acc, 0, 0, 0);
                sf[kt] = acc;
            }
            const bool diag = (t == dg[qs]);
            const int qloc = wave * 16 + l15;  // local q within tile
            float ls = 0.f;
            u16 pb[16];
#pragma unroll
            for (int kt = 0; kt < 4; ++kt)
#pragma unroll
                for (int r = 0; r < 4; ++r) {
                    float v = sf[kt][r];
                    if (diag && (kt * 16 + quad * 4 + r > qloc)) v = -INFINITY;
                    float p = __builtin_amdgcn_exp2f(v);
                    ls += p;
                    pb[kt * 4 + r] = f2bt(p);
                }
            lacc[qs] += ls;
            // P^T C-layout -> LDS (swizzled) -> B-frags
#pragma unroll
            for (int kt = 0; kt < 4; ++kt) {
                const int g = kt * 16 + quad * 4;
                const int pos = ((g >> 3) ^ (l15 & 7)) * 8 + (g & 7);
                *(u16x4*)(pw + l15 * 64 + pos) =
                    u16x4{pb[kt * 4], pb[kt * 4 + 1], pb[kt * 4 + 2], pb[kt * 4 + 3]};
            }
            bf16x8 pf0 = *(const bf16x8*)(pw + l15 * 64 + ((quad    ) ^ (l15 & 7)) * 8);
            bf16x8 pf1 = *(const bf16x8*)(pw + l15 * 64 + ((quad + 4) ^ (l15 & 7)) * 8);
            // ctx^T += Vt.P^T
#pragma unroll
            for (int dt = 0; dt < 4; ++dt) {
                of[qs][dt] = __builtin_amdgcn_mfma_f32_16x16x32_bf16(vf[dt][0], pf0, of[qs][dt], 0, 0, 0);
                of[qs][dt] = __builtin_amdgcn_mfma_f32_16x16x32_bf16(vf[dt][1], pf1, of[qs][dt], 0, 0, 0);
            }
        }
    }

    // Epilogue per q-subtile: reduce l, normalize, transpose via LDS, store.
#pragma unroll
    for (int qs = 0; qs < 4; ++qs) {
        float ls = lacc[qs];
        ls += __shfl_xor(ls, 16);
        ls += __shfl_xor(ls, 32);
        const float inv = 1.f / ls;
#pragma unroll
        for (int dt = 0; dt < 4; ++dt) {
            const int g = dt * 16 + quad * 4;
            const int pos = ((g >> 3) ^ (l15 & 7)) * 8 + (g & 7);
            *(u16x4*)(pw + l15 * 64 + pos) =
                u16x4{f2b(of[qs][dt][0] * inv), f2b(of[qs][dt][1] * inv),
                      f2b(of[qs][dt][2] * inv), f2b(of[qs][dt][3] * inv)};
        }
        const int r  = lane >> 2;
        const int cp = lane & 3;
        u16x8 o0 = *(const u16x8*)(pw + r * 64 + ((2 * cp    ) ^ (r & 7)) * 8);
        u16x8 o1 = *(const u16x8*)(pw + r * 64 + ((2 * cp + 1) ^ (r & 7)) * 8);
        u16* op = Om + ((size_t)(b * S_ + dg[qs] * 64 + wave * 16 + r)) * D_ + h * 64 + cp * 16;
        *(u16x8*)op = o0;
        *(u16x8*)(op + 8) = o1;
    }
}

// ---------------------------------------------------------------------------
extern "C" void kernel_launch(void* const* d_in, const int* in_sizes, int n_in,
                              void* d_out, int out_size, void* d_ws, size_t ws_size,
                              hipStream_t stream)
{
    (void)in_sizes; (void)n_in; (void)out_size; (void)ws_size;
    const float* x  = (const float*)d_in[0];
    const float* Wq = (const float*)d_in[1];
    const float* bq = (const float*)d_in[2];
    const float* Wk = (const float*)d_in[3];
    const float* bk = (const float*)d_in[4];
    const float* Wv = (const float*)d_in[5];
    const float* bv = (const float*)d_in[6];
    const float* Wo = (const float*)d_in[7];
    const float* bo = (const float*)d_in[8];

    const float cscale = 0.18033688011112042f;  // log2(e)/sqrt(64)

    u16* ws = (u16*)d_ws;
    const size_t MD = (size_t)M_ * D_;
    const size_t DD = (size_t)D_ * D_;
    u16* xb  = ws;            // bf16 [M, D]
    u16* Qb  = xb + MD;       // bf16 [B,S,H,HD], pre-scaled
    u16* Kb  = Qb + MD;       // bf16 [B,S,H,HD]
    u16* Vtb = Kb + MD;       // bf16 [B,H,HD,S]
    u16* Cb  = Vtb + MD;      // ctx bf16 [M, D]
    u16* WqT = Cb + MD;
    u16* WkT = WqT + DD;
    u16* WvT = WkT + DD;
    u16* WoT = WvT + DD;

    cvt_k<<<M_ * D_ / 2048, 256, 0, stream>>>(x, xb);

    dim3 tg(D_ / 32, D_ / 32), tb(32, 8);
    transpose_k<<<tg, tb, 0, stream>>>(Wq, WqT, D_, D_, cscale);
    transpose_k<<<tg, tb, 0, stream>>>(Wk, WkT, D_, D_, 1.0f);
    transpose_k<<<tg, tb, 0, stream>>>(Wv, WvT, D_, D_, 1.0f);
    transpose_k<<<tg, tb, 0, stream>>>(Wo, WoT, D_, D_, 1.0f);

    dim3 gg(D_ / BN, M_ / BM);  // (8, 64)
    gemm_bias_k<0><<<gg, 256, 0, stream>>>(xb, WqT, bq, cscale, Qb,  M_, D_, D_);
    gemm_bias_k<0><<<gg, 256, 0, stream>>>(xb, WkT, bk, 1.0f,   Kb,  M_, D_, D_);
    gemm_bias_k<2><<<gg, 256, 0, stream>>>(xb, WvT, bv, 1.0f,   Vtb, M_, D_, D_);

    attn_mfma_k<<<dim3(8, B_ * H_), 256, 0, stream>>>(Qb, Kb, Vtb, Cb);

    gemm_bias_k<1><<<gg, 256, 0, stream>>>(Cb, WoT, bo, 1.0f, d_out, M_, D_, D_);
}